// Round 1
// baseline (155.660 us; speedup 1.0000x reference)
//
#include <hip/hip_runtime.h>

// TurnEmbedding: out[b,s,o] = sum_t sum_p turns[token_ids[b,s], t]^p * poly_coeffs[t,p,o]
// BATCH=32 SEQ=8192 VOCAB=50257 N_TURNS=4 P=4 OUT_DIM=128
// Write-bound: 128 MiB fp32 output vs ~5 MiB reads. Strategy: coalesced float4
// stores, per-thread register-resident coefficients (16 x float4, loop-invariant),
// Horner evaluation per turn. No LDS needed.

constexpr int N_TOKENS = 32 * 8192;   // 262144
constexpr int OUT_DIM  = 128;
constexpr int N_TURNS  = 4;
constexpr int P        = 4;

constexpr int BLOCK         = 256;
constexpr int TOK_PER_ITER  = BLOCK / 32;          // 8 tokens per block-iteration
constexpr int GRID          = 2048;
constexpr int TOK_PER_BLOCK = N_TOKENS / GRID;     // 128
constexpr int ITERS         = TOK_PER_BLOCK / TOK_PER_ITER; // 16

__device__ __forceinline__ float4 f4_fma(float a, const float4 b, const float4 c) {
    return make_float4(fmaf(a, b.x, c.x),
                       fmaf(a, b.y, c.y),
                       fmaf(a, b.z, c.z),
                       fmaf(a, b.w, c.w));
}

__device__ __forceinline__ float4 f4_add(const float4 a, const float4 b) {
    return make_float4(a.x + b.x, a.y + b.y, a.z + b.z, a.w + b.w);
}

__global__ __launch_bounds__(BLOCK) void TurnEmbedding_50053548867731_kernel(
    const int*    __restrict__ token_ids,   // (N_TOKENS)
    const float4* __restrict__ turns,       // (VOCAB) rows, each one float4 (N_TURNS=4)
    const float*  __restrict__ coeffs,      // (N_TURNS, P, OUT_DIM)
    float4*       __restrict__ out)         // (N_TOKENS, OUT_DIM/4)
{
    const int tid  = threadIdx.x;
    const int slot = tid >> 5;      // 0..7 : token slot within block-iteration
    const int o4   = tid & 31;      // which float4 of the 32 per token

    // Loop-invariant coefficient fragments: c[t][p] = coeffs[t, p, o4*4 .. o4*4+3]
    float4 c[N_TURNS][P];
#pragma unroll
    for (int t = 0; t < N_TURNS; ++t)
#pragma unroll
        for (int p = 0; p < P; ++p)
            c[t][p] = *reinterpret_cast<const float4*>(coeffs + (t * P + p) * OUT_DIM + o4 * 4);

    const int base = blockIdx.x * TOK_PER_BLOCK + slot;

#pragma unroll 2
    for (int it = 0; it < ITERS; ++it) {
        const int tok = base + it * TOK_PER_ITER;

        const int id = token_ids[tok];         // broadcast within half-wave
        const float4 x4 = turns[id];           // 16B gather, L2-resident table

        float xs[N_TURNS] = {x4.x, x4.y, x4.z, x4.w};

        float4 acc = make_float4(0.f, 0.f, 0.f, 0.f);
#pragma unroll
        for (int t = 0; t < N_TURNS; ++t) {
            const float x = xs[t];
            // Horner: ((c3*x + c2)*x + c1)*x + c0
            float4 r = f4_fma(x, c[t][3], c[t][2]);
            r = f4_fma(x, r, c[t][1]);
            r = f4_fma(x, r, c[t][0]);
            acc = f4_add(acc, r);
        }

        out[tok * (OUT_DIM / 4) + o4] = acc;   // contiguous 512B per half-wave
    }
}

extern "C" void kernel_launch(void* const* d_in, const int* in_sizes, int n_in,
                              void* d_out, int out_size, void* d_ws, size_t ws_size,
                              hipStream_t stream) {
    const int*   token_ids = (const int*)d_in[0];
    const float* turns     = (const float*)d_in[1];
    const float* coeffs    = (const float*)d_in[2];
    float*       out       = (float*)d_out;

    TurnEmbedding_50053548867731_kernel<<<GRID, BLOCK, 0, stream>>>(
        token_ids,
        reinterpret_cast<const float4*>(turns),
        coeffs,
        reinterpret_cast<float4*>(out));
}

// Round 3
// 153.257 us; speedup vs baseline: 1.0157x; 1.0157x over previous
//
#include <hip/hip_runtime.h>

// TurnEmbedding: out[b,s,o] = sum_t sum_p turns[token_ids[b,s], t]^p * poly_coeffs[t,p,o]
// BATCH=32 SEQ=8192 VOCAB=50257 N_TURNS=4 P=4 OUT_DIM=128
//
// Write-bound kernel: 134 MB fp32 out vs ~5 MB reads. Floor ~21 us @6.3 TB/s.
// R2 -> R3: __builtin_nontemporal_store needs a clang ext_vector_type, not
// HIP's float4 class — store via native vector. Logic unchanged from R2:
//  - batch-prefetch 8 ids then 8 turn-gathers (independent loads in flight)
//  - nontemporal stores (keep 800KB turns table resident in 4MiB/XCD L2)
//  - folded constant term, pure-FMA Horner (12 FMA/token/thread)

constexpr int N_TOKENS = 32 * 8192;   // 262144
constexpr int OUT_DIM  = 128;
constexpr int N_TURNS  = 4;

constexpr int BLOCK         = 256;
constexpr int TOK_PER_ITER  = BLOCK / 32;               // 8 tokens per block-iteration
constexpr int GRID          = 2048;
constexpr int TOK_PER_BLOCK = N_TOKENS / GRID;          // 128
constexpr int ITERS         = TOK_PER_BLOCK / TOK_PER_ITER; // 16
constexpr int GROUP         = 8;                        // prefetch depth

typedef float floatx4 __attribute__((ext_vector_type(4)));

__device__ __forceinline__ floatx4 f4_fma(float a, const floatx4 b, const floatx4 c) {
    floatx4 r;
    r.x = fmaf(a, b.x, c.x);
    r.y = fmaf(a, b.y, c.y);
    r.z = fmaf(a, b.z, c.z);
    r.w = fmaf(a, b.w, c.w);
    return r;
}

__global__ __launch_bounds__(BLOCK) void TurnEmbedding_50053548867731_kernel(
    const int*     __restrict__ token_ids,   // (N_TOKENS)
    const floatx4* __restrict__ turns,       // (VOCAB) rows, one float4 each
    const float*   __restrict__ coeffs,      // (N_TURNS, P=4, OUT_DIM)
    floatx4*       __restrict__ out)         // (N_TOKENS, OUT_DIM/4)
{
    const int tid  = threadIdx.x;
    const int slot = tid >> 5;      // 0..7 : token slot within block-iteration
    const int o4   = tid & 31;      // which float4 of the 32 per token

    // Loop-invariant coefficients. Degree-0 terms folded into one sum.
    floatx4 c1[N_TURNS], c2[N_TURNS], c3[N_TURNS];
    floatx4 c0sum = (floatx4)(0.f);
#pragma unroll
    for (int t = 0; t < N_TURNS; ++t) {
        const float* base_t = coeffs + (t * 4) * OUT_DIM + o4 * 4;
        c0sum = c0sum + *reinterpret_cast<const floatx4*>(base_t + 0 * OUT_DIM);
        c1[t] = *reinterpret_cast<const floatx4*>(base_t + 1 * OUT_DIM);
        c2[t] = *reinterpret_cast<const floatx4*>(base_t + 2 * OUT_DIM);
        c3[t] = *reinterpret_cast<const floatx4*>(base_t + 3 * OUT_DIM);
    }

    const int base = blockIdx.x * TOK_PER_BLOCK + slot;

#pragma unroll
    for (int g = 0; g < ITERS / GROUP; ++g) {
        // Phase 1: 8 independent id loads in flight
        int ids[GROUP];
#pragma unroll
        for (int i = 0; i < GROUP; ++i)
            ids[i] = token_ids[base + (g * GROUP + i) * TOK_PER_ITER];

        // Phase 2: 8 independent 16B gathers in flight (L2-resident table)
        floatx4 xs[GROUP];
#pragma unroll
        for (int i = 0; i < GROUP; ++i)
            xs[i] = turns[ids[i]];

        // Phase 3: compute + streaming store
#pragma unroll
        for (int i = 0; i < GROUP; ++i) {
            const int tok = base + (g * GROUP + i) * TOK_PER_ITER;
            const float xv[N_TURNS] = {xs[i].x, xs[i].y, xs[i].z, xs[i].w};

            floatx4 acc = c0sum;
#pragma unroll
            for (int t = 0; t < N_TURNS; ++t) {
                const float x = xv[t];
                // acc += x*(c1 + x*(c2 + x*c3))  — 3 FMA per component
                floatx4 r = f4_fma(x, c3[t], c2[t]);
                r = f4_fma(x, r, c1[t]);
                acc = f4_fma(x, r, acc);
            }

            __builtin_nontemporal_store(acc, &out[tok * (OUT_DIM / 4) + o4]);
        }
    }
}

extern "C" void kernel_launch(void* const* d_in, const int* in_sizes, int n_in,
                              void* d_out, int out_size, void* d_ws, size_t ws_size,
                              hipStream_t stream) {
    const int*   token_ids = (const int*)d_in[0];
    const float* turns     = (const float*)d_in[1];
    const float* coeffs    = (const float*)d_in[2];

    TurnEmbedding_50053548867731_kernel<<<GRID, BLOCK, 0, stream>>>(
        token_ids,
        reinterpret_cast<const floatx4*>(turns),
        coeffs,
        reinterpret_cast<floatx4*>(d_out));
}

// Round 4
// 148.096 us; speedup vs baseline: 1.0511x; 1.0348x over previous
//
#include <hip/hip_runtime.h>

// TurnEmbedding: out[b,s,o] = sum_t sum_p turns[token_ids[b,s], t]^p * poly_coeffs[t,p,o]
// BATCH=32 SEQ=8192 VOCAB=50257 N_TURNS=4 P=4 OUT_DIM=128
//
// Write-bound: 134 MB fp32 out vs ~4 MB reads. Kernel floor ~21 us @6.3 TB/s.
// Timed region also contains harness poisons (512 MiB ws + 134 MB out) ->
// ~135-140 us floor for dur_us regardless of kernel.
// R3 -> R4 (discriminating experiment): plain write-back stores (the 6.3 TB/s
// fill kernel uses plain stores — NT is the unproven path) + GROUP=4 prefetch
// (halves prefetch VGPRs, more waves/SIMD). Neutral result => kernel is at its
// write floor and dur_us is harness-dominated.

constexpr int N_TOKENS = 32 * 8192;   // 262144
constexpr int OUT_DIM  = 128;
constexpr int N_TURNS  = 4;

constexpr int BLOCK         = 256;
constexpr int TOK_PER_ITER  = BLOCK / 32;               // 8 tokens per block-iteration
constexpr int GRID          = 2048;
constexpr int TOK_PER_BLOCK = N_TOKENS / GRID;          // 128
constexpr int ITERS         = TOK_PER_BLOCK / TOK_PER_ITER; // 16
constexpr int GROUP         = 4;                        // prefetch depth

typedef float floatx4 __attribute__((ext_vector_type(4)));

__device__ __forceinline__ floatx4 f4_fma(float a, const floatx4 b, const floatx4 c) {
    floatx4 r;
    r.x = fmaf(a, b.x, c.x);
    r.y = fmaf(a, b.y, c.y);
    r.z = fmaf(a, b.z, c.z);
    r.w = fmaf(a, b.w, c.w);
    return r;
}

__global__ __launch_bounds__(BLOCK) void TurnEmbedding_50053548867731_kernel(
    const int*     __restrict__ token_ids,   // (N_TOKENS)
    const floatx4* __restrict__ turns,       // (VOCAB) rows, one float4 each
    const float*   __restrict__ coeffs,      // (N_TURNS, P=4, OUT_DIM)
    floatx4*       __restrict__ out)         // (N_TOKENS, OUT_DIM/4)
{
    const int tid  = threadIdx.x;
    const int slot = tid >> 5;      // 0..7 : token slot within block-iteration
    const int o4   = tid & 31;      // which float4 of the 32 per token

    // Loop-invariant coefficients. Degree-0 terms folded into one sum.
    floatx4 c1[N_TURNS], c2[N_TURNS], c3[N_TURNS];
    floatx4 c0sum = (floatx4)(0.f);
#pragma unroll
    for (int t = 0; t < N_TURNS; ++t) {
        const float* base_t = coeffs + (t * 4) * OUT_DIM + o4 * 4;
        c0sum = c0sum + *reinterpret_cast<const floatx4*>(base_t + 0 * OUT_DIM);
        c1[t] = *reinterpret_cast<const floatx4*>(base_t + 1 * OUT_DIM);
        c2[t] = *reinterpret_cast<const floatx4*>(base_t + 2 * OUT_DIM);
        c3[t] = *reinterpret_cast<const floatx4*>(base_t + 3 * OUT_DIM);
    }

    const int base = blockIdx.x * TOK_PER_BLOCK + slot;

#pragma unroll
    for (int g = 0; g < ITERS / GROUP; ++g) {
        // Phase 1: independent id loads in flight
        int ids[GROUP];
#pragma unroll
        for (int i = 0; i < GROUP; ++i)
            ids[i] = token_ids[base + (g * GROUP + i) * TOK_PER_ITER];

        // Phase 2: independent 16B gathers in flight (L2-resident table)
        floatx4 xs[GROUP];
#pragma unroll
        for (int i = 0; i < GROUP; ++i)
            xs[i] = turns[ids[i]];

        // Phase 3: compute + plain write-back store
#pragma unroll
        for (int i = 0; i < GROUP; ++i) {
            const int tok = base + (g * GROUP + i) * TOK_PER_ITER;
            const float xv[N_TURNS] = {xs[i].x, xs[i].y, xs[i].z, xs[i].w};

            floatx4 acc = c0sum;
#pragma unroll
            for (int t = 0; t < N_TURNS; ++t) {
                const float x = xv[t];
                floatx4 r = f4_fma(x, c3[t], c2[t]);
                r = f4_fma(x, r, c1[t]);
                acc = f4_fma(x, r, acc);
            }

            out[tok * (OUT_DIM / 4) + o4] = acc;
        }
    }
}

extern "C" void kernel_launch(void* const* d_in, const int* in_sizes, int n_in,
                              void* d_out, int out_size, void* d_ws, size_t ws_size,
                              hipStream_t stream) {
    const int*   token_ids = (const int*)d_in[0];
    const float* turns     = (const float*)d_in[1];
    const float* coeffs    = (const float*)d_in[2];

    TurnEmbedding_50053548867731_kernel<<<GRID, BLOCK, 0, stream>>>(
        token_ids,
        reinterpret_cast<const floatx4*>(turns),
        coeffs,
        reinterpret_cast<floatx4*>(d_out));
}

// Round 5
// 139.648 us; speedup vs baseline: 1.1147x; 1.0605x over previous
//
#include <hip/hip_runtime.h>

// TurnEmbedding: out[b,s,o] = sum_t sum_p turns[token_ids[b,s], t]^p * poly_coeffs[t,p,o]
// BATCH=32 SEQ=8192 VOCAB=50257 N_TURNS=4 P=4 OUT_DIM=128
//
// Write-bound: 134 MB fp32 out vs ~4 MB reads. Kernel floor ~21 us @6.3 TB/s.
// dur_us also contains harness poisons (537 MB ws + 134 MB out) -> ~123 us
// traffic floor for the whole replay.
//
// R4 -> R5: two-phase structure. Phase 1 gathers all 128 of the block's turn
// vectors into LDS in one burst (128 independent loads in flight, ONE latency
// hop per block). Phase 2 is a pure store stream: broadcast LDS read (same
// address within half-wave -> conflict-free), 12 FMAs, coalesced float4 store,
// no global-load dependence in the loop. Plain write-back stores (R4 winner).

constexpr int N_TOKENS = 32 * 8192;   // 262144
constexpr int OUT_DIM  = 128;
constexpr int N_TURNS  = 4;

constexpr int BLOCK         = 256;
constexpr int GRID          = 2048;
constexpr int TOK_PER_BLOCK = N_TOKENS / GRID;          // 128
constexpr int TOK_PER_ITER  = BLOCK / 32;               // 8
constexpr int ITERS         = TOK_PER_BLOCK / TOK_PER_ITER; // 16

typedef float floatx4 __attribute__((ext_vector_type(4)));

__device__ __forceinline__ floatx4 f4_fma(float a, const floatx4 b, const floatx4 c) {
    floatx4 r;
    r.x = fmaf(a, b.x, c.x);
    r.y = fmaf(a, b.y, c.y);
    r.z = fmaf(a, b.z, c.z);
    r.w = fmaf(a, b.w, c.w);
    return r;
}

__global__ __launch_bounds__(BLOCK) void TurnEmbedding_50053548867731_kernel(
    const int*     __restrict__ token_ids,   // (N_TOKENS)
    const floatx4* __restrict__ turns,       // (VOCAB) rows, one float4 each
    const float*   __restrict__ coeffs,      // (N_TURNS, P=4, OUT_DIM)
    floatx4*       __restrict__ out)         // (N_TOKENS, OUT_DIM/4)
{
    __shared__ floatx4 xbuf[TOK_PER_BLOCK];  // 2 KB

    const int tid   = threadIdx.x;
    const int slot  = tid >> 5;     // 0..7 : token slot within iteration
    const int o4    = tid & 31;     // which float4 of the 32 per token
    const int base0 = blockIdx.x * TOK_PER_BLOCK;

    // Phase 1: burst-gather all 128 token vectors for this block into LDS.
    // 128 independent id-loads then 128 independent 16B gathers in flight.
    if (tid < TOK_PER_BLOCK) {
        const int id = token_ids[base0 + tid];
        xbuf[tid] = turns[id];
    }

    // Loop-invariant coefficients (overlaps with phase-1 latency).
    // Degree-0 terms folded into one sum.
    floatx4 c1[N_TURNS], c2[N_TURNS], c3[N_TURNS];
    floatx4 c0sum = (floatx4)(0.f);
#pragma unroll
    for (int t = 0; t < N_TURNS; ++t) {
        const float* base_t = coeffs + (t * 4) * OUT_DIM + o4 * 4;
        c0sum = c0sum + *reinterpret_cast<const floatx4*>(base_t + 0 * OUT_DIM);
        c1[t] = *reinterpret_cast<const floatx4*>(base_t + 1 * OUT_DIM);
        c2[t] = *reinterpret_cast<const floatx4*>(base_t + 2 * OUT_DIM);
        c3[t] = *reinterpret_cast<const floatx4*>(base_t + 3 * OUT_DIM);
    }

    __syncthreads();

    // Phase 2: pure streaming expansion. No global loads in the loop.
#pragma unroll
    for (int it = 0; it < ITERS; ++it) {
        const int t_local = it * TOK_PER_ITER + slot;
        const floatx4 x4 = xbuf[t_local];     // LDS broadcast, conflict-free
        const float xv[N_TURNS] = {x4.x, x4.y, x4.z, x4.w};

        floatx4 acc = c0sum;
#pragma unroll
        for (int t = 0; t < N_TURNS; ++t) {
            const float x = xv[t];
            floatx4 r = f4_fma(x, c3[t], c2[t]);
            r = f4_fma(x, r, c1[t]);
            acc = f4_fma(x, r, acc);
        }

        out[(base0 + t_local) * (OUT_DIM / 4) + o4] = acc;
    }
}

extern "C" void kernel_launch(void* const* d_in, const int* in_sizes, int n_in,
                              void* d_out, int out_size, void* d_ws, size_t ws_size,
                              hipStream_t stream) {
    const int*   token_ids = (const int*)d_in[0];
    const float* turns     = (const float*)d_in[1];
    const float* coeffs    = (const float*)d_in[2];

    TurnEmbedding_50053548867731_kernel<<<GRID, BLOCK, 0, stream>>>(
        token_ids,
        reinterpret_cast<const floatx4*>(turns),
        coeffs,
        reinterpret_cast<floatx4*>(d_out));
}